// Round 6
// baseline (202.823 us; speedup 1.0000x reference)
//
#include <hip/hip_runtime.h>
#include <cstdint>

// Problem constants: B=32, T=D=256, rows R = B*T = 8192, K = 256.
#define R_TOT 8192
#define KD    256
#define SLOT  ((size_t)R_TOT * KD)            // elements per bf16 matrix (2,097,152)
// ws layout (bytes):
#define IVN_OFF  0                            // 64 f32: 1/frobenius-norm [ten][j]
#define ICN_OFF  256                          // 2*8192 f32: 1/col-norm [ten][j][s]
#define CSQ_OFF  (ICN_OFF + 65536)            // 8 tc-partials x 2*8192 f32 = 512 KB (R5 bug: was 256 KB)
#define MATS_OFF (CSQ_OFF + 524288)           // 2 bf16 mats (Vb, Ab), swizzled, 8.4 MB
#define PART_OFF (MATS_OFF + (size_t)2 * SLOT * 2)  // 2 bf16 partials, 8.4 MB

typedef float f32x4 __attribute__((ext_vector_type(4)));
typedef short s16x8 __attribute__((ext_vector_type(8)));   // 8 bf16 (4 VGPRs)

__device__ __forceinline__ unsigned short bf16rne(float x){
  union { float f; uint32_t u; } c; c.f = x;
  return (unsigned short)((c.u + 0x7fffu + ((c.u >> 16) & 1u)) >> 16);
}
__device__ __forceinline__ float bf2f(unsigned short u){
  union { uint32_t u; float f; } c; c.u = ((uint32_t)u) << 16; return c.f;
}
__device__ __forceinline__ void glds16(const void* g, void* l){
  __builtin_amdgcn_global_load_lds((const __attribute__((address_space(1))) uint32_t*)g,
                                   (__attribute__((address_space(3))) uint32_t*)l, 16, 0, 0);
}

// Cast V,A -> bf16 swizzled images AND write per-tc column sum-of-squares partials.
// Image row r = j*256 + t, k-dim = d; 16B chunk c of row r stored at c ^ (r&7).
// Grid (tc=8, j=32, ten=2), 256 thr. Block covers 32 t-rows x 256 d.
// csq partial slot: [(tc*2+ten)*32 + j]*256 + s  (every slot written -> no zeroing)
__global__ void cast_ns_k(const float* __restrict__ V, const float* __restrict__ A,
                          unsigned short* __restrict__ mats, float* __restrict__ csq){
  const int tc = blockIdx.x, j = blockIdx.y, ten = blockIdx.z;
  const int tid = threadIdx.x;
  const int chunk = tid & 31;                  // d-chunk (8 floats)
  const int tsub  = tid >> 5;                  // 0..7
  const float* X = (ten ? A : V) + (size_t)j * 65536;
  unsigned short* M = mats + (size_t)ten * SLOT + (size_t)j * 65536;
  float cs[8];
  #pragma unroll
  for (int e = 0; e < 8; ++e) cs[e] = 0.f;
  #pragma unroll
  for (int tt = 0; tt < 4; ++tt){
    const int t = tc * 32 + tt * 8 + tsub;
    const float4 p0 = *(const float4*)(X + t * 256 + chunk * 8);
    const float4 p1 = *(const float4*)(X + t * 256 + chunk * 8 + 4);
    cs[0] += p0.x * p0.x; cs[1] += p0.y * p0.y; cs[2] += p0.z * p0.z; cs[3] += p0.w * p0.w;
    cs[4] += p1.x * p1.x; cs[5] += p1.y * p1.y; cs[6] += p1.z * p1.z; cs[7] += p1.w * p1.w;
    s16x8 o;
    o[0] = (short)bf16rne(p0.x); o[1] = (short)bf16rne(p0.y);
    o[2] = (short)bf16rne(p0.z); o[3] = (short)bf16rne(p0.w);
    o[4] = (short)bf16rne(p1.x); o[5] = (short)bf16rne(p1.y);
    o[6] = (short)bf16rne(p1.z); o[7] = (short)bf16rne(p1.w);
    *(s16x8*)(M + (size_t)t * 256 + ((chunk ^ (t & 7)) << 3)) = o;
  }
  __shared__ float red[8][256];
  #pragma unroll
  for (int e = 0; e < 8; ++e) red[tsub][chunk * 8 + e] = cs[e];
  __syncthreads();
  float s = 0.f;
  #pragma unroll
  for (int g = 0; g < 8; ++g) s += red[g][tid];
  csq[(size_t)((tc * 2 + ten) * 32 + j) * 256 + tid] = s;
}

// Finish norms: sum 8 tc-partials; icn = rsqrt, ivn = rsqrt of row-sum. Grid (32, 2).
__global__ void nreduce_k(const float* __restrict__ csq, float* __restrict__ ivn,
                          float* __restrict__ icn){
  const int j = blockIdx.x, ten = blockIdx.y, s = threadIdx.x;
  float c = 0.f;
  #pragma unroll
  for (int tc = 0; tc < 8; ++tc)
    c += csq[(size_t)((tc * 2 + ten) * 32 + j) * 256 + s];
  icn[ten * 8192 + j * 256 + s] = rsqrtf(c + 1e-18f);
  __shared__ float red[256];
  red[s] = c; __syncthreads();
  for (int off = 128; off > 0; off >>= 1){
    if (s < off) red[s] += red[s + off];
    __syncthreads();
  }
  if (s == 0) ivn[ten * 32 + j] = rsqrtf(red[0] + 1e-18f);
}

// v5b: occupancy attack (R5 retry, ws overrun fixed). Block tile 128 rows x 32 cols,
// wave tile 64x16; col tile 16KB x2 dbuf (32KB LDS) -> 3 blocks/CU (12 waves/CU),
// 1024 blocks. A-frags (128 VGPRs) resident; B via global_load_lds w=16.
__global__ __launch_bounds__(256, 3) void gemm_exp_k(const unsigned short* __restrict__ mats,
                                                     const float* __restrict__ ivn,
                                                     const float* __restrict__ icn,
                                                     unsigned short* __restrict__ part){
  __shared__ __align__(16) char smem[32768];          // 2 x 16KB B buffers; epilogue reuse
  const int tid  = threadIdx.x;
  const int lane = tid & 63;
  const int w    = tid >> 6;
  const int wm   = (w & 1) * 64;        // wave row offset in 128-row block tile
  const int wn   = (w >> 1) * 16;       // wave col offset in 32-col block tile
  const int lm   = lane & 15;
  const int kh   = lane >> 4;           // 0..3
  const int dir  = blockIdx.x;
  const int s0   = blockIdx.y * 32;
  const int rb   = blockIdx.z;
  const int r0   = rb * 128;
  const int ib   = rb >> 1;             // batch index of this row tile (excluded diagonal)

  const unsigned short* rowmat = mats + (size_t)dir * SLOT;        // dir0: Vb, dir1: Ab
  const unsigned short* colmat = mats + (size_t)(1 - dir) * SLOT;  // the other one
  const float sivn = ivn[dir * 32 + ib] * 1.44269504088896340736f; // row scale * log2e
  const float* icnb = icn + (size_t)(1 - dir) * 8192 + s0 + wn + lm;  // this lane's col scale

  // A-fragments (m = r0+wm+mi*16+lm, chunk = (ks*4+kh) ^ (lm&7)) from swizzled image.
  s16x8 afr[4][8];
  #pragma unroll
  for (int mi = 0; mi < 4; ++mi){
    const unsigned short* rp = rowmat + (size_t)(r0 + wm + mi * 16 + lm) * 256;
    #pragma unroll
    for (int ks = 0; ks < 8; ++ks)
      afr[mi][ks] = *(const s16x8*)(rp + (((ks * 4 + kh) ^ (lm & 7)) << 3));
  }
  #pragma unroll
  for (int mi = 0; mi < 4; ++mi)
    #pragma unroll
    for (int ks = 0; ks < 8; ++ks)
      asm volatile("" : "+v"(afr[mi][ks]));

  // ds_read base: addr(ks) = n*512 + (((ks*4+kh) ^ (n&7))<<4), n = wn+lm.
  // pbase (ks even) / palt = pbase^64 (ks odd), + (ks>>1)*128 as imm.
  const int nn = wn + lm;
  const int pbase = nn * 512 + ((kh ^ (nn & 3)) << 4) + (((nn >> 2) & 1) << 6);
  const int palt  = pbase ^ 64;

  f32x4 acc[4];
  #pragma unroll
  for (int mi = 0; mi < 4; ++mi)
    acc[mi] = f32x4{0.f, 0.f, 0.f, 0.f};

  // Preload j(0) into buffer 0. 16KB = 4 chunks/thread.
  {
    const int j0 = (ib == 0) ? 1 : 0;
    const char* src = (const char*)colmat + ((size_t)j0 * 256 + s0) * 512;
    #pragma unroll
    for (int c = 0; c < 4; ++c)
      glds16(src + (size_t)(c * 256 + tid) * 16, smem + (c * 256 + w * 64) * 16);
  }
  __syncthreads();

  for (int jj = 0; jj < 31; ++jj){
    const int j = jj + (jj >= ib ? 1 : 0);
    if (jj < 30){
      const int jn = (jj + 1) + ((jj + 1) >= ib ? 1 : 0);
      const char* src = (const char*)colmat + ((size_t)jn * 256 + s0) * 512;
      char* dst = smem + (((jj + 1) & 1) << 14);
      #pragma unroll
      for (int c = 0; c < 4; ++c)
        glds16(src + (size_t)(c * 256 + tid) * 16, dst + (c * 256 + w * 64) * 16);
    }

    const float csc = sivn * icnb[j * 256];     // per-j column scale (1 scalar/lane)

    const char* rbuf = smem + ((jj & 1) << 14);
    f32x4 S[4];
    #pragma unroll
    for (int mi = 0; mi < 4; ++mi)
      S[mi] = f32x4{0.f, 0.f, 0.f, 0.f};

    #pragma unroll
    for (int ks = 0; ks < 8; ++ks){
      const int immo = (ks >> 1) * 128;
      s16x8 b = *(const s16x8*)(rbuf + ((ks & 1) ? palt : pbase) + immo);
      #pragma unroll
      for (int mi = 0; mi < 4; ++mi)
        S[mi] = __builtin_amdgcn_mfma_f32_16x16x32_bf16(afr[mi][ks], b, S[mi], 0, 0, 0);
    }
    #pragma unroll
    for (int mi = 0; mi < 4; ++mi)
      #pragma unroll
      for (int r = 0; r < 4; ++r)
        acc[mi][r] += __builtin_amdgcn_exp2f(S[mi][r] * csc);

    __syncthreads();   // readers done with rbuf; prefetch drained for next iter
  }

  // Epilogue: C/D layout (col = lane&15, row = (lane>>4)*4 + reg) -> LDS -> coalesced bf16.
  unsigned short* ebuf = (unsigned short*)smem;       // [128][40] ushorts = 10 KB
  #pragma unroll
  for (int mi = 0; mi < 4; ++mi){
    const int n = wn + lm;
    #pragma unroll
    for (int r = 0; r < 4; ++r){
      const int m = wm + mi * 16 + (kh << 2) + r;
      ebuf[m * 40 + n] = bf16rne(acc[mi][r]);
    }
  }
  __syncthreads();
  unsigned short* P = part + (size_t)dir * SLOT;
  #pragma unroll
  for (int p = 0; p < 2; ++p){
    const int q   = tid + p * 256;     // 0..511 (16B units of the 128x32 tile)
    const int row = q >> 2;
    const int c8  = q & 3;
    s16x8 v = *(const s16x8*)(&ebuf[row * 40 + c8 * 8]);
    *(s16x8*)(&P[(size_t)(r0 + row) * 256 + s0 + c8 * 8]) = v;
  }
}

__global__ void combine_k(const unsigned short* __restrict__ part, float* __restrict__ out){
  const int idx = blockIdx.x * 256 + threadIdx.x;   // 262144 ushort8 units
  s16x8 a = ((const s16x8*)part)[idx];
  s16x8 b = ((const s16x8*)(part + (size_t)R_TOT * 256))[idx];
  float4 o0, o1;
  o0.x = -(__logf(1.f + bf2f((unsigned short)a[0])) + __logf(1.f + bf2f((unsigned short)b[0])));
  o0.y = -(__logf(1.f + bf2f((unsigned short)a[1])) + __logf(1.f + bf2f((unsigned short)b[1])));
  o0.z = -(__logf(1.f + bf2f((unsigned short)a[2])) + __logf(1.f + bf2f((unsigned short)b[2])));
  o0.w = -(__logf(1.f + bf2f((unsigned short)a[3])) + __logf(1.f + bf2f((unsigned short)b[3])));
  o1.x = -(__logf(1.f + bf2f((unsigned short)a[4])) + __logf(1.f + bf2f((unsigned short)b[4])));
  o1.y = -(__logf(1.f + bf2f((unsigned short)a[5])) + __logf(1.f + bf2f((unsigned short)b[5])));
  o1.z = -(__logf(1.f + bf2f((unsigned short)a[6])) + __logf(1.f + bf2f((unsigned short)b[6])));
  o1.w = -(__logf(1.f + bf2f((unsigned short)a[7])) + __logf(1.f + bf2f((unsigned short)b[7])));
  ((float4*)out)[idx * 2]     = o0;
  ((float4*)out)[idx * 2 + 1] = o1;
}

extern "C" void kernel_launch(void* const* d_in, const int* in_sizes, int n_in,
                              void* d_out, int out_size, void* d_ws, size_t ws_size,
                              hipStream_t stream){
  const float* V = (const float*)d_in[2];   // back_VF  (pre_VF/pre_AF unused by reference)
  const float* A = (const float*)d_in[3];   // back_AF
  float* out = (float*)d_out;
  float* ivn = (float*)((char*)d_ws + IVN_OFF);
  float* icn = (float*)((char*)d_ws + ICN_OFF);
  float* csq = (float*)((char*)d_ws + CSQ_OFF);
  unsigned short* mats = (unsigned short*)((char*)d_ws + MATS_OFF);
  unsigned short* part = (unsigned short*)((char*)d_ws + PART_OFF);

  cast_ns_k<<<dim3(8, 32, 2), 256, 0, stream>>>(V, A, mats, csq);
  nreduce_k<<<dim3(32, 2), 256, 0, stream>>>(csq, ivn, icn);
  gemm_exp_k<<<dim3(2, 8, 64), 256, 0, stream>>>(mats, ivn, icn, part);
  combine_k<<<1024, 256, 0, stream>>>(part, out);
}

// Round 7
// 130.283 us; speedup vs baseline: 1.5568x; 1.5568x over previous
//
#include <hip/hip_runtime.h>
#include <cstdint>

// Problem constants: B=32, T=D=256, rows R = B*T = 8192, K = 256.
#define R_TOT 8192
#define KD    256
#define SLOT  ((size_t)R_TOT * KD)            // elements per image (2,097,152); fp8 -> also bytes
// ws layout (bytes):
#define IVN_OFF  0                            // 64 f32: 1/frobenius-norm [ten][j]
#define ICN_OFF  256                          // 2*8192 f32: 1/col-norm [ten][j][s]
#define CSQ_OFF  (ICN_OFF + 65536)            // 8 tc-partials x 2*8192 f32 = 512 KB
#define MATS_OFF (CSQ_OFF + 524288)           // 2 fp8 images (Vq, Aq), permuted+swizzled, 4 MB
#define PART_OFF (MATS_OFF + 2 * SLOT)        // 2 bf16 partials, 8.4 MB

typedef float f32x4 __attribute__((ext_vector_type(4)));
typedef short s16x8 __attribute__((ext_vector_type(8)));   // 16B (part stores)
typedef long  lx2   __attribute__((ext_vector_type(2)));   // 16B = 2 fp8 MFMA operands

__device__ __forceinline__ unsigned short bf16rne(float x){
  union { float f; uint32_t u; } c; c.f = x;
  return (unsigned short)((c.u + 0x7fffu + ((c.u >> 16) & 1u)) >> 16);
}
__device__ __forceinline__ float bf2f(unsigned short u){
  union { uint32_t u; float f; } c; c.u = ((uint32_t)u) << 16; return c.f;
}
__device__ __forceinline__ void glds16(const void* g, void* l){
  __builtin_amdgcn_global_load_lds((const __attribute__((address_space(1))) uint32_t*)g,
                                   (__attribute__((address_space(3))) uint32_t*)l, 16, 0, 0);
}

// Image byte layout per 256-B row r (k = 0..255):
//   t = k>>6, half = (k>>5)&1, kh = (k>>3)&3, lo = k&7
//   chunk q = t*4 + kh, stored at 16B slot (q ^ (r&15)), byte half*8 + lo.
// => one ds_read_b128 at slot ((t*4+kh) ^ (r&15)) yields the fp8 MFMA fragments
//    (8 B each) for k-chunks 2t and 2t+1 at quad kh; XOR swizzle -> <=2-way banks.
__global__ void cast_ns_k(const float* __restrict__ V, const float* __restrict__ A,
                          unsigned char* __restrict__ mats, float* __restrict__ csq){
  const int tc = blockIdx.x, j = blockIdx.y, ten = blockIdx.z;
  const int tid = threadIdx.x;
  const int g    = tid & 31;                 // d-chunk of 8 floats
  const int tsub = tid >> 5;                 // 0..7
  const int q    = ((g >> 3) << 2) | (g & 3);
  const int half = (g >> 2) & 1;
  const float* X = (ten ? A : V) + (size_t)j * 65536;
  unsigned char* M = mats + (size_t)ten * SLOT + (size_t)j * 65536;
  float cs[8];
  #pragma unroll
  for (int e = 0; e < 8; ++e) cs[e] = 0.f;
  #pragma unroll
  for (int tt = 0; tt < 4; ++tt){
    const int t = tc * 32 + tt * 8 + tsub;
    const float4 p0 = *(const float4*)(X + t * 256 + g * 8);
    const float4 p1 = *(const float4*)(X + t * 256 + g * 8 + 4);
    cs[0] += p0.x * p0.x; cs[1] += p0.y * p0.y; cs[2] += p0.z * p0.z; cs[3] += p0.w * p0.w;
    cs[4] += p1.x * p1.x; cs[5] += p1.y * p1.y; cs[6] += p1.z * p1.z; cs[7] += p1.w * p1.w;
    int d0 = __builtin_amdgcn_cvt_pk_fp8_f32(p0.x, p0.y, 0, false);
    d0     = __builtin_amdgcn_cvt_pk_fp8_f32(p0.z, p0.w, d0, true);
    int d1 = __builtin_amdgcn_cvt_pk_fp8_f32(p1.x, p1.y, 0, false);
    d1     = __builtin_amdgcn_cvt_pk_fp8_f32(p1.z, p1.w, d1, true);
    int2 o; o.x = d0; o.y = d1;
    *(int2*)(M + (size_t)t * 256 + (((q ^ (t & 15)) << 4) | (half << 3))) = o;
  }
  __shared__ float red[8][256];
  #pragma unroll
  for (int e = 0; e < 8; ++e) red[tsub][g * 8 + e] = cs[e];
  __syncthreads();
  float s = 0.f;
  #pragma unroll
  for (int gg = 0; gg < 8; ++gg) s += red[gg][tid];
  csq[(size_t)((tc * 2 + ten) * 32 + j) * 256 + tid] = s;
}

// Finish norms: sum 8 tc-partials; icn = rsqrt, ivn = rsqrt of row-sum. Grid (32, 2).
__global__ void nreduce_k(const float* __restrict__ csq, float* __restrict__ ivn,
                          float* __restrict__ icn){
  const int j = blockIdx.x, ten = blockIdx.y, s = threadIdx.x;
  float c = 0.f;
  #pragma unroll
  for (int tc = 0; tc < 8; ++tc)
    c += csq[(size_t)((tc * 2 + ten) * 32 + j) * 256 + s];
  icn[ten * 8192 + j * 256 + s] = rsqrtf(c + 1e-18f);
  __shared__ float red[256];
  red[s] = c; __syncthreads();
  for (int off = 128; off > 0; off >>= 1){
    if (s < off) red[s] += red[s + off];
    __syncthreads();
  }
  if (s == 0) ivn[ten * 32 + j] = rsqrtf(red[0] + 1e-18f);
}

// v6: fp8 MFMA. Block tile 128 rows x 32 cols, 4 waves of 32x32; afr = 32 VGPRs,
// ~92 live regs -> __launch_bounds__(256,4): 4 blocks/CU (16 waves/CU), exact grid
// pack (1024 blocks / 256 CUs). B tile 8KB x2 dbuf (16KB LDS) via global_load_lds.
__global__ __launch_bounds__(256, 4) void gemm_exp_k(const unsigned char* __restrict__ mats,
                                                     const float* __restrict__ ivn,
                                                     const float* __restrict__ icn,
                                                     unsigned short* __restrict__ part){
  __shared__ __align__(16) char smem[16384];          // 2 x 8KB B buffers; epilogue reuse
  const int tid  = threadIdx.x;
  const int lane = tid & 63;
  const int w    = tid >> 6;
  const int wm   = w * 32;              // wave row offset in 128-row block tile
  const int lm   = lane & 15;
  const int kh   = lane >> 4;           // 0..3
  const int dir  = blockIdx.x;
  const int s0   = blockIdx.y * 32;
  const int rb   = blockIdx.z;
  const int r0   = rb * 128;
  const int ib   = rb >> 1;             // batch index of this row tile (excluded diagonal)

  const unsigned char* rowmat = mats + (size_t)dir * SLOT;        // dir0: Vq, dir1: Aq
  const unsigned char* colmat = mats + (size_t)(1 - dir) * SLOT;  // the other one
  const float sivn = ivn[dir * 32 + ib] * 1.44269504088896340736f; // row scale * log2e
  const float* icnb = icn + (size_t)(1 - dir) * 8192 + s0 + lm;

  // A-fragments: m = r0 + wm + mi*16 + lm; slot (t*4+kh) ^ (m&15), m&15 == lm.
  lx2 afr[2][4];
  #pragma unroll
  for (int mi = 0; mi < 2; ++mi){
    const unsigned char* rp = rowmat + (size_t)(r0 + wm + mi * 16 + lm) * 256;
    #pragma unroll
    for (int t = 0; t < 4; ++t)
      afr[mi][t] = *(const lx2*)(rp + (((((t << 2) | kh)) ^ lm) << 4));
  }
  #pragma unroll
  for (int mi = 0; mi < 2; ++mi)
    #pragma unroll
    for (int t = 0; t < 4; ++t)
      asm volatile("" : "+v"(afr[mi][t]));

  // ds_read addrs (j-invariant): addr(ni,t) = nl*256 + (((t*4+kh) ^ (nl&15))<<4),
  // nl = ni*16 + lm  =>  ni=1 adds 4096 (imm).  Decompose XOR on bits 6-7:
  int a4[4];
  {
    const int base  = lm * 256 + ((kh ^ (lm & 3)) << 4);   // bits 6-7 clear
    const int base2 = base ^ ((lm >> 2) << 6);
    #pragma unroll
    for (int t = 0; t < 4; ++t) a4[t] = base2 ^ (t << 6);
  }

  f32x4 acc[2][2];
  #pragma unroll
  for (int mi = 0; mi < 2; ++mi)
    #pragma unroll
    for (int ni = 0; ni < 2; ++ni)
      acc[mi][ni] = f32x4{0.f, 0.f, 0.f, 0.f};

  // Preload j(0) into buffer 0 (8 KB = 2 chunks/thread).
  {
    const int j0 = (ib == 0) ? 1 : 0;
    const unsigned char* src = colmat + ((size_t)j0 * 256 + s0) * 256;
    #pragma unroll
    for (int c = 0; c < 2; ++c)
      glds16(src + (size_t)(c * 256 + tid) * 16, smem + (c * 256 + w * 64) * 16);
  }
  __syncthreads();

  for (int jj = 0; jj < 31; ++jj){
    const int j = jj + (jj >= ib ? 1 : 0);
    if (jj < 30){
      const int jn = (jj + 1) + ((jj + 1) >= ib ? 1 : 0);
      const unsigned char* src = colmat + ((size_t)jn * 256 + s0) * 256;
      char* dst = smem + (((jj + 1) & 1) << 13);
      #pragma unroll
      for (int c = 0; c < 2; ++c)
        glds16(src + (size_t)(c * 256 + tid) * 16, dst + (c * 256 + w * 64) * 16);
    }

    const float csc0 = sivn * icnb[j * 256];
    const float csc1 = sivn * icnb[j * 256 + 16];

    const char* rbuf = smem + ((jj & 1) << 13);
    f32x4 S[2][2];
    #pragma unroll
    for (int mi = 0; mi < 2; ++mi)
      #pragma unroll
      for (int ni = 0; ni < 2; ++ni)
        S[mi][ni] = f32x4{0.f, 0.f, 0.f, 0.f};

    #pragma unroll
    for (int t = 0; t < 4; ++t){
      lx2 b0 = *(const lx2*)(rbuf + a4[t]);
      lx2 b1 = *(const lx2*)(rbuf + a4[t] + 4096);
      S[0][0] = __builtin_amdgcn_mfma_f32_16x16x32_fp8_fp8(afr[0][t][0], b0[0], S[0][0], 0, 0, 0);
      S[1][0] = __builtin_amdgcn_mfma_f32_16x16x32_fp8_fp8(afr[1][t][0], b0[0], S[1][0], 0, 0, 0);
      S[0][1] = __builtin_amdgcn_mfma_f32_16x16x32_fp8_fp8(afr[0][t][0], b1[0], S[0][1], 0, 0, 0);
      S[1][1] = __builtin_amdgcn_mfma_f32_16x16x32_fp8_fp8(afr[1][t][0], b1[0], S[1][1], 0, 0, 0);
      S[0][0] = __builtin_amdgcn_mfma_f32_16x16x32_fp8_fp8(afr[0][t][1], b0[1], S[0][0], 0, 0, 0);
      S[1][0] = __builtin_amdgcn_mfma_f32_16x16x32_fp8_fp8(afr[1][t][1], b0[1], S[1][0], 0, 0, 0);
      S[0][1] = __builtin_amdgcn_mfma_f32_16x16x32_fp8_fp8(afr[0][t][1], b1[1], S[0][1], 0, 0, 0);
      S[1][1] = __builtin_amdgcn_mfma_f32_16x16x32_fp8_fp8(afr[1][t][1], b1[1], S[1][1], 0, 0, 0);
    }
    #pragma unroll
    for (int mi = 0; mi < 2; ++mi)
      #pragma unroll
      for (int r = 0; r < 4; ++r){
        acc[mi][0][r] += __builtin_amdgcn_exp2f(S[mi][0][r] * csc0);
        acc[mi][1][r] += __builtin_amdgcn_exp2f(S[mi][1][r] * csc1);
      }

    __syncthreads();   // readers done with rbuf; prefetch drained for next iter
  }

  // Epilogue: C/D layout (col = lane&15, row = (lane>>4)*4 + reg) -> LDS -> coalesced bf16.
  unsigned short* ebuf = (unsigned short*)smem;       // [128][40] ushorts = 10 KB
  #pragma unroll
  for (int mi = 0; mi < 2; ++mi)
    #pragma unroll
    for (int ni = 0; ni < 2; ++ni){
      const int n = ni * 16 + lm;
      #pragma unroll
      for (int r = 0; r < 4; ++r){
        const int m = wm + mi * 16 + (kh << 2) + r;
        ebuf[m * 40 + n] = bf16rne(acc[mi][ni][r]);
      }
    }
  __syncthreads();
  unsigned short* P = part + (size_t)dir * SLOT;
  #pragma unroll
  for (int p = 0; p < 2; ++p){
    const int q   = tid + p * 256;     // 0..511 (16B units of the 128x32 tile)
    const int row = q >> 2;
    const int c8  = q & 3;
    s16x8 v = *(const s16x8*)(&ebuf[row * 40 + c8 * 8]);
    *(s16x8*)(&P[(size_t)(r0 + row) * 256 + s0 + c8 * 8]) = v;
  }
}

__global__ void combine_k(const unsigned short* __restrict__ part, float* __restrict__ out){
  const int idx = blockIdx.x * 256 + threadIdx.x;   // 262144 ushort8 units
  s16x8 a = ((const s16x8*)part)[idx];
  s16x8 b = ((const s16x8*)(part + (size_t)R_TOT * 256))[idx];
  float4 o0, o1;
  o0.x = -(__logf(1.f + bf2f((unsigned short)a[0])) + __logf(1.f + bf2f((unsigned short)b[0])));
  o0.y = -(__logf(1.f + bf2f((unsigned short)a[1])) + __logf(1.f + bf2f((unsigned short)b[1])));
  o0.z = -(__logf(1.f + bf2f((unsigned short)a[2])) + __logf(1.f + bf2f((unsigned short)b[2])));
  o0.w = -(__logf(1.f + bf2f((unsigned short)a[3])) + __logf(1.f + bf2f((unsigned short)b[3])));
  o1.x = -(__logf(1.f + bf2f((unsigned short)a[4])) + __logf(1.f + bf2f((unsigned short)b[4])));
  o1.y = -(__logf(1.f + bf2f((unsigned short)a[5])) + __logf(1.f + bf2f((unsigned short)b[5])));
  o1.z = -(__logf(1.f + bf2f((unsigned short)a[6])) + __logf(1.f + bf2f((unsigned short)b[6])));
  o1.w = -(__logf(1.f + bf2f((unsigned short)a[7])) + __logf(1.f + bf2f((unsigned short)b[7])));
  ((float4*)out)[idx * 2]     = o0;
  ((float4*)out)[idx * 2 + 1] = o1;
}

extern "C" void kernel_launch(void* const* d_in, const int* in_sizes, int n_in,
                              void* d_out, int out_size, void* d_ws, size_t ws_size,
                              hipStream_t stream){
  const float* V = (const float*)d_in[2];   // back_VF  (pre_VF/pre_AF unused by reference)
  const float* A = (const float*)d_in[3];   // back_AF
  float* out = (float*)d_out;
  float* ivn = (float*)((char*)d_ws + IVN_OFF);
  float* icn = (float*)((char*)d_ws + ICN_OFF);
  float* csq = (float*)((char*)d_ws + CSQ_OFF);
  unsigned char* mats = (unsigned char*)((char*)d_ws + MATS_OFF);
  unsigned short* part = (unsigned short*)((char*)d_ws + PART_OFF);

  cast_ns_k<<<dim3(8, 32, 2), 256, 0, stream>>>(V, A, mats, csq);
  nreduce_k<<<dim3(32, 2), 256, 0, stream>>>(csq, ivn, icn);
  gemm_exp_k<<<dim3(2, 8, 64), 256, 0, stream>>>(mats, ivn, icn, part);
  combine_k<<<1024, 256, 0, stream>>>(part, out);
}